// Round 4
// baseline (59496.106 us; speedup 1.0000x reference)
//
#include <hip/hip_runtime.h>

#define HH 128      // hidden size
#define G4 512      // 4*HH gates
#define TT 102400   // sequence length
#define BB 8        // batch

typedef _Float16 v2h __attribute__((ext_vector_type(2)));
typedef _Float16 v8h __attribute__((ext_vector_type(8)));
typedef float    f4v __attribute__((ext_vector_type(4)));

#define MFMA16(A, B, C) __builtin_amdgcn_mfma_f32_16x16x32_f16((A), (B), (C), 0, 0, 0)

#if __has_builtin(__builtin_amdgcn_fdot2)
#define FDOT2(a, b, c) __builtin_amdgcn_fdot2((a), (b), (c), false)
#else
static __device__ __forceinline__ float fdot2_fb(v2h a, v2h b, float c) {
    return fmaf((float)a[0], (float)b[0], fmaf((float)a[1], (float)b[1], c));
}
#define FDOT2(a, b, c) fdot2_fb((a), (b), (c))
#endif

// DPP lane move (VALU pipe): 0xB1=xor1(quad), 0x4E=xor2(quad), 0x141=xor7(row-half mirror)
template<int CTRL>
__device__ __forceinline__ float dpp_mov(float v) {
    return __int_as_float(
        __builtin_amdgcn_update_dpp(0, __float_as_int(v), CTRL, 0xF, 0xF, true));
}

__device__ __forceinline__ float tanh_f(float x) {
    return fmaf(2.0f, __builtin_amdgcn_rcpf(1.0f + __expf(-2.0f * x)), -1.0f);
}
__device__ __forceinline__ float sigm_f(float x) {
    return __builtin_amdgcn_rcpf(1.0f + __expf(-x));
}

union HI { int i; v2h h; };

// ---------------------------------------------------------------------------
// R7-verified reduce-to-distinct dot (kept for stage B only).
// ---------------------------------------------------------------------------
__device__ __forceinline__ float dotred(const v2h w[8][8],
                                        const _Float16* __restrict__ hsl,
                                        bool bp1, bool bp2, bool bp3) {
    const int4* hp4 = (const int4*)hsl;     // 2x ds_read_b128 (16 halfs)
    int4 ha = hp4[0], hb = hp4[1];
    int hp[8] = {ha.x, ha.y, ha.z, ha.w, hb.x, hb.y, hb.z, hb.w};
    float acc[8];
#pragma unroll
    for (int r = 0; r < 8; ++r) acc[r] = 0.f;
#pragma unroll
    for (int i = 0; i < 8; ++i) {
        HI u; u.i = hp[i];
#pragma unroll
        for (int r = 0; r < 8; ++r) acc[r] = FDOT2(w[r][i], u.h, acc[r]);
    }
    float b0[4];
#pragma unroll
    for (int m = 0; m < 4; ++m) {
        float send = bp1 ? acc[2 * m] : acc[2 * m + 1];
        float keep = bp1 ? acc[2 * m + 1] : acc[2 * m];
        b0[m] = keep + dpp_mov<0xB1>(send);
    }
    float d0[2];
#pragma unroll
    for (int i = 0; i < 2; ++i) {
        float send = bp2 ? b0[i] : b0[i + 2];
        float keep = bp2 ? b0[i + 2] : b0[i];
        d0[i] = keep + dpp_mov<0x4E>(send);
    }
    float send = bp3 ? d0[0] : d0[1];
    float keep = bp3 ? d0[1] : d0[0];
    return keep + dpp_mov<0x141>(send);
}

// stage-B weight slice loader (fp16), unchanged
__device__ __forceinline__ void load_w8h(const float* __restrict__ W,
                                         int Q, int j, v2h w[8][8]) {
#pragma unroll
    for (int r = 0; r < 8; ++r) {
        int row = 2 * Q + (r & 1) + 128 * (r >> 1);
        const float4* rp = (const float4*)(W + (size_t)row * HH + 16 * j);
#pragma unroll
        for (int i = 0; i < 4; ++i) {
            float4 f = rp[i];
            w[r][2 * i]     = (v2h){(_Float16)f.x, (_Float16)f.y};
            w[r][2 * i + 1] = (v2h){(_Float16)f.z, (_Float16)f.w};
        }
    }
}

// ---------------------------------------------------------------------------
// R14 = R13 (MFMA chain) with plain __syncthreads() barriers.
//   R12 measured the vmcnt-drain cost of __syncthreads at -0.2% (noise), so
//   the inline-asm light barrier buys nothing and is the only rule-#18-class
//   hazard (hipcc hoisting reg-only MFMA past inline-asm waitcnt). Dropped.
// Chain: wave wv owns row-tiles {wv, wv+8, wv+16, wv+24} = gates {i,f,g,o}
//   of cells [16wv,16wv+16). B = h broadcast into all 16 cols -> every lane
//   holds complete row-dots. D map (m89-verified): row=(lane>>4)*4+reg,
//   col=lane&15. Active lanes (lane&15<4) own cell 16wv+4*(lane>>4)+(lane&3)
//   and hold all 4 gates of it in acc[g][lane&3] -> no cross-lane gather.
//   Bias folded into MFMA C-in.
// ---------------------------------------------------------------------------
__global__ void __launch_bounds__(512, 2)
lstm_slot_kernel(
    const float* __restrict__ x,
    const float* __restrict__ Wih0, const float* __restrict__ Whh0,
    const float* __restrict__ bih0, const float* __restrict__ bhh0,
    const float* __restrict__ Wih1, const float* __restrict__ Whh1,
    const float* __restrict__ bih1, const float* __restrict__ bhh1,
    float* __restrict__ h1s, float* __restrict__ c1s,
    float* __restrict__ h2s, float* __restrict__ c2s,
    double* __restrict__ pooled,
    _Float16* __restrict__ h1ring,  // [2][B][chunkT][HH]   fp16
    float* __restrict__ xpring,     // [2][B][chunkT][HH][4] (t,cell,gate) fp32
    int c, int chunkT, int nchunks)
{
    __shared__ __align__(32) _Float16 hh[2 * HH];
    const int t = threadIdx.x;

    if (blockIdx.x < 16) {
        // =============== chain stages (A: layer0, C: layer1) ===============
        const bool isA = (blockIdx.x < 8);
        const int cc = isA ? c : (c - 2);
        if (cc < 0 || cc >= nchunks) return;
        const int b = blockIdx.x & 7;

        const int l   = t & 63;
        const int wv  = t >> 6;          // wave 0..7
        const int lhi = l >> 4;          // 0..3 (D row-block / B k-block)
        const int lq  = l & 3;
        const int koff = 8 * lhi;        // halfs
        const bool act_lane = ((l & 12) == 0);      // lane&15 < 4
        const int cellw = 16 * wv + 4 * lhi + lq;   // cell owned by act lanes
        const bool s0_ = (l & 1) != 0, s1_ = (l & 2) != 0;

        // ---- A-fragments: af[g][kt]; A row = lane&15, k = 8*(lane>>4)+j ----
        const float* Wc = isA ? Whh0 : Whh1;
        v8h af[4][4];
#pragma unroll
        for (int g = 0; g < 4; ++g) {
            const float* wr = Wc + (size_t)(16 * wv + 128 * g + (l & 15)) * HH;
#pragma unroll
            for (int kt = 0; kt < 4; ++kt) {
                const f4v* p = (const f4v*)(wr + 32 * kt + koff);
                f4v fa = p[0], fb = p[1];
                v8h v;
                v[0] = (_Float16)fa[0]; v[1] = (_Float16)fa[1];
                v[2] = (_Float16)fa[2]; v[3] = (_Float16)fa[3];
                v[4] = (_Float16)fb[0]; v[5] = (_Float16)fb[1];
                v[6] = (_Float16)fb[2]; v[7] = (_Float16)fb[3];
                af[g][kt] = v;
            }
        }
        // bias in C-in (A only; layer1 bias already inside xp from stage B)
        f4v cin[4] = {{0,0,0,0},{0,0,0,0},{0,0,0,0},{0,0,0,0}};
        float wih_[4] = {0.f, 0.f, 0.f, 0.f};
        if (isA) {
#pragma unroll
            for (int g = 0; g < 4; ++g) {
#pragma unroll
                for (int r = 0; r < 4; ++r) {
                    int row = 16 * wv + 128 * g + 4 * lhi + r;
                    cin[g][r] = bih0[row] + bhh0[row];
                }
                wih_[g] = Wih0[cellw + 128 * g];
            }
        }

        float* hst = isA ? h1s : h2s;
        float* cst = isA ? c1s : c2s;
        float c_reg = cst[b * HH + cellw];
        if (t < HH) hh[t] = (_Float16)hst[b * HH + t];

        _Float16* rp = h1ring + ((size_t)((c & 1) * BB + b)) * (size_t)chunkT * HH;
        const float* xrow = x + (size_t)b * TT + (size_t)cc * chunkT;
        const float* xpp = xpring
            + ((size_t)((cc & 1) * BB + b)) * (size_t)chunkT * G4 + 4 * cellw;

        // input prefetch, 1 pair ahead (independent of recurrence)
        float xt0 = 0.f, xt1 = 0.f;
        f4v xp0 = {0,0,0,0}, xp1 = {0,0,0,0};
        if (isA) { xt0 = xrow[0]; xt1 = xrow[1]; }
        else if (act_lane) {
            xp0 = *(const f4v*)(xpp);
            xp1 = *(const f4v*)(xpp + G4);
        }
        const float* xrp = xrow + 2;
        const float* xpn = xpp + 2 * (size_t)G4;

        double pacc = 0.0;
        float hfin = 0.f;
        __syncthreads();

#define CHAIN_STEP(PAR, XT, XP) do {                                          \
        const _Float16* hb_ = hh + (PAR) * HH + koff;                         \
        v8h b0_ = *(const v8h*)(hb_);                                         \
        v8h b1_ = *(const v8h*)(hb_ + 32);                                    \
        v8h b2_ = *(const v8h*)(hb_ + 64);                                    \
        v8h b3_ = *(const v8h*)(hb_ + 96);                                    \
        f4v a0_ = MFMA16(af[0][0], b0_, cin[0]);                              \
        f4v a1_ = MFMA16(af[1][0], b0_, cin[1]);                              \
        f4v a2_ = MFMA16(af[2][0], b0_, cin[2]);                              \
        f4v a3_ = MFMA16(af[3][0], b0_, cin[3]);                              \
        a0_ = MFMA16(af[0][1], b1_, a0_); a1_ = MFMA16(af[1][1], b1_, a1_);   \
        a2_ = MFMA16(af[2][1], b1_, a2_); a3_ = MFMA16(af[3][1], b1_, a3_);   \
        a0_ = MFMA16(af[0][2], b2_, a0_); a1_ = MFMA16(af[1][2], b2_, a1_);   \
        a2_ = MFMA16(af[2][2], b2_, a2_); a3_ = MFMA16(af[3][2], b2_, a3_);   \
        a0_ = MFMA16(af[0][3], b3_, a0_); a1_ = MFMA16(af[1][3], b3_, a1_);   \
        a2_ = MFMA16(af[2][3], b3_, a2_); a3_ = MFMA16(af[3][3], b3_, a3_);   \
        float q01_, q23_, si_, sf_, sg2_, so_;                                \
        q01_ = s0_ ? a0_[1] : a0_[0]; q23_ = s0_ ? a0_[3] : a0_[2];           \
        si_  = s1_ ? q23_ : q01_;                                             \
        q01_ = s0_ ? a1_[1] : a1_[0]; q23_ = s0_ ? a1_[3] : a1_[2];           \
        sf_  = s1_ ? q23_ : q01_;                                             \
        q01_ = s0_ ? a2_[1] : a2_[0]; q23_ = s0_ ? a2_[3] : a2_[2];           \
        sg2_ = s1_ ? q23_ : q01_;                                             \
        q01_ = s0_ ? a3_[1] : a3_[0]; q23_ = s0_ ? a3_[3] : a3_[2];           \
        so_  = s1_ ? q23_ : q01_;                                             \
        if (act_lane) {                                                       \
            float pi_, pf_, pg_, po_;                                         \
            if (isA) {                                                        \
                pi_ = fmaf(XT, wih_[0], si_);                                 \
                pf_ = fmaf(XT, wih_[1], sf_);                                 \
                pg_ = fmaf(XT, wih_[2], sg2_);                                \
                po_ = fmaf(XT, wih_[3], so_);                                 \
            } else {                                                          \
                pi_ = si_ + XP[0]; pf_ = sf_ + XP[1];                         \
                pg_ = sg2_ + XP[2]; po_ = so_ + XP[3];                        \
            }                                                                 \
            float gi_ = sigm_f(pi_), gf_ = sigm_f(pf_);                       \
            float gg_ = tanh_f(pg_), go_ = sigm_f(po_);                       \
            c_reg = fmaf(gf_, c_reg, gi_ * gg_);                              \
            float hv_ = go_ * tanh_f(c_reg);                                  \
            hfin = hv_;                                                       \
            hh[(((PAR) ^ 1)) * HH + cellw] = (_Float16)hv_;                   \
            if (isA) rp[cellw] = (_Float16)hv_;                               \
            else     pacc += (double)hv_;                                     \
        }                                                                     \
        rp += HH;                                                             \
        __syncthreads();                                                      \
    } while (0)

        for (int s = 0; s < chunkT; s += 2) {
            float xt2 = 0.f, xt3 = 0.f;
            f4v xp2 = {0,0,0,0}, xp3 = {0,0,0,0};
            const bool p2 = (s + 2 < chunkT);       // chunkT even
            if (isA) {
                if (p2) { xt2 = xrp[0]; xt3 = xrp[1]; }
            } else if (act_lane && p2) {
                xp2 = *(const f4v*)(xpn);
                xp3 = *(const f4v*)(xpn + G4);
            }
            CHAIN_STEP(0, xt0, xp0);
            CHAIN_STEP(1, xt1, xp1);
            xt0 = xt2; xt1 = xt3; xp0 = xp2; xp1 = xp3;
            xrp += 2; xpn += 2 * (size_t)G4;
        }
#undef CHAIN_STEP

        if (act_lane) {
            cst[b * HH + cellw] = c_reg;
            hst[b * HH + cellw] = hfin;
            if (!isA) pooled[b * HH + cellw] += pacc;
        }

    } else {
        // ---------------- stage B: xp1 = Wih1 @ h1 + bias, chunk c-1 -------
        const int bc = c - 1;
        if (bc < 0 || bc >= nchunks) return;
        const int Q = t >> 3;
        const int j = t & 7;
        const bool bp1 = ((j ^ (j >> 2)) & 1) != 0;
        const bool bp2 = ((j ^ (j >> 1)) & 1) != 0;
        const bool bp3 = ((j >> 2) & 1) != 0;
        const int cellj = bp1 ? 1 : 0;
        const int gatej = (bp2 ? 2 : 0) + (bp3 ? 1 : 0);
        const int myc   = 2 * Q + cellj;
        const int myrow = myc + 128 * gatej;

        const int ib = blockIdx.x - 16;       // 0..63
        const int bb = ib >> 3;               // batch
        const int sl = ib & 7;                // t-slice (stride 8)
        v2h w[8][8];
        load_w8h(Wih1, Q, j, w);
        const float bias_l = bih1[myrow] + bhh1[myrow];
        const _Float16* hrp = h1ring
            + ((size_t)((bc & 1) * BB + bb)) * (size_t)chunkT * HH;
        float* xpw = xpring + ((size_t)((bc & 1) * BB + bb)) * (size_t)chunkT * G4;
        if (t < HH) hh[t] = hrp[(size_t)sl * HH + t];
        __syncthreads();
        int pb = 0;
        for (int tt = sl; tt < chunkT; tt += 8) {
            int ttn = tt + 8;
            bool pf = (t < HH) && (ttn < chunkT);
            _Float16 hn = (_Float16)0.f;
            if (pf) hn = hrp[(size_t)ttn * HH + t];          // prefetch
            float sfin = dotred(w, hh + pb * HH + 16 * j, bp1, bp2, bp3);
            if (pf) hh[(pb ^ 1) * HH + t] = hn;
            xpw[(size_t)tt * G4 + 4 * myc + gatej] = sfin + bias_l;
            __syncthreads();
            pb ^= 1;
        }
    }
}

// ---------------- head: mean-pool (done) -> FC+ReLU -> FC ------------------
__global__ void head_kernel(const double* __restrict__ pooled,
                            const float* __restrict__ fcW1, const float* __restrict__ fcb1,
                            const float* __restrict__ fcW2, const float* __restrict__ fcb2,
                            float* __restrict__ out)
{
    __shared__ float p_s[HH];
    __shared__ float hid_s[64];
    const int b = blockIdx.x, t = threadIdx.x;
    if (t < HH) p_s[t] = (float)(pooled[b * HH + t] * (1.0 / (double)TT));
    __syncthreads();
    if (t < 64) {
        float acc = fcb1[t];
#pragma unroll 8
        for (int k = 0; k < HH; ++k) acc = fmaf(p_s[k], fcW1[t * HH + k], acc);
        hid_s[t] = fmaxf(acc, 0.f);
    }
    __syncthreads();
    if (t < 11) {
        float acc = fcb2[t];
#pragma unroll
        for (int k = 0; k < 64; ++k) acc = fmaf(hid_s[k], fcW2[t * 64 + k], acc);
        out[b * 11 + t] = acc;
    }
}

// ---------------------------------------------------------------------------
extern "C" void kernel_launch(void* const* d_in, const int* in_sizes, int n_in,
                              void* d_out, int out_size, void* d_ws, size_t ws_size,
                              hipStream_t stream)
{
    const float* x    = (const float*)d_in[0];
    const float* Wih0 = (const float*)d_in[1];
    const float* Whh0 = (const float*)d_in[2];
    const float* bih0 = (const float*)d_in[3];
    const float* bhh0 = (const float*)d_in[4];
    const float* Wih1 = (const float*)d_in[5];
    const float* Whh1 = (const float*)d_in[6];
    const float* bih1 = (const float*)d_in[7];
    const float* bhh1 = (const float*)d_in[8];
    const float* fcW1 = (const float*)d_in[9];
    const float* fcb1 = (const float*)d_in[10];
    const float* fcW2 = (const float*)d_in[11];
    const float* fcb2 = (const float*)d_in[12];
    float* out = (float*)d_out;

    // ---- workspace layout ----
    char* wsp = (char*)d_ws;
    float*  h1s    = (float*) (wsp + 0);
    float*  c1s    = (float*) (wsp + 4096);
    float*  h2s    = (float*) (wsp + 8192);
    float*  c2s    = (float*) (wsp + 12288);
    double* pooled = (double*)(wsp + 16384);          // 8 KB
    const size_t STATE_BYTES = 24576;

    // per-t ring bytes: h1 fp16 4096 + xp fp32 32768 = 36864
    static const int cands[] = {800, 400, 160, 80, 40, 8};
    int chunkT = 8;
    for (int i = 0; i < 6; ++i) {
        size_t need = STATE_BYTES + (size_t)36864 * (size_t)cands[i];
        if (need <= ws_size) { chunkT = cands[i]; break; }
    }
    const int nchunks = TT / chunkT;

    _Float16* h1ring = (_Float16*)(wsp + STATE_BYTES);
    float* xpring = (float*)(wsp + STATE_BYTES + (size_t)2 * BB * chunkT * HH * 2);

    // zero persistent state (h/c/pooled); ws is re-poisoned before every call
    hipMemsetAsync(d_ws, 0, STATE_BYTES, stream);

    // pipeline: slot c runs A(c) || B(c-1) || C(c-2)
    const int nslots = nchunks + 2;
    for (int c = 0; c < nslots; ++c) {
        lstm_slot_kernel<<<80, 512, 0, stream>>>(
            x, Wih0, Whh0, bih0, bhh0, Wih1, Whh1, bih1, bhh1,
            h1s, c1s, h2s, c2s, pooled, h1ring, xpring,
            c, chunkT, nchunks);
    }
    head_kernel<<<BB, 128, 0, stream>>>(pooled, fcW1, fcb1, fcW2, fcb2, out);
}